// Round 10
// baseline (131.330 us; speedup 1.0000x reference)
//
#include <hip/hip_runtime.h>
#include <math.h>

#define NOBS 7
#define PI_F 3.14159265358979f

// ---- Layout ----
// Block = 1024 threads = 16 waves. Wave wv = h7*8 + h6*4 + s :
//   s  = ancilla value (0..3), h6 = wire-6 value, h7 = wire-7 value.
// Each wave holds 64 main amplitudes, 1 per lane:
//   main index m (wire w -> bit 7-w) = (lane<<2) | (h6<<1) | h7,
//   lane bit (5-w) = wire w for w=0..5.
// q = h7*2 + h6 (in 0..3). Exchange buffer slot = lane*17 + s*4 + q
// (stride 17 float2 -> conflict-free). Double-buffered by site parity.
//
// d_ws layout (floats): [0..31] X1 rows (float2[s][sp]), [32..63] X2,
// [64..95] F, [96..103] a0[s], [104..167] qtab (32 float2), [168..231] freqs.

// ---- VALU-only cross-lane xor exchange ----
template<int LM>
__device__ __forceinline__ float lane_partner(float x) {
  if constexpr (LM == 1) {
    return __int_as_float(__builtin_amdgcn_mov_dpp(__float_as_int(x), 0xB1, 0xF, 0xF, true));
  } else if constexpr (LM == 2) {
    return __int_as_float(__builtin_amdgcn_mov_dpp(__float_as_int(x), 0x4E, 0xF, 0xF, true));
  } else if constexpr (LM == 4) {
    int a = __builtin_amdgcn_mov_dpp(__float_as_int(x), 0x1B, 0xF, 0xF, true);   // xor3
    return __int_as_float(__builtin_amdgcn_mov_dpp(a, 0x141, 0xF, 0xF, true));   // xor7 -> net xor4
  } else if constexpr (LM == 8) {
    int a = __builtin_amdgcn_mov_dpp(__float_as_int(x), 0x141, 0xF, 0xF, true);  // xor7
    return __int_as_float(__builtin_amdgcn_mov_dpp(a, 0x140, 0xF, 0xF, true));   // xor15 -> net xor8
  } else if constexpr (LM == 16) {
#if __has_builtin(__builtin_amdgcn_permlane16_swap)
    unsigned xu = __float_as_uint(x);
    auto r = __builtin_amdgcn_permlane16_swap(xu, xu, false, false);
    return (__uint_as_float(r[0]) + __uint_as_float(r[1])) - x;
#else
    return __shfl_xor(x, 16, 64);
#endif
  } else {
#if __has_builtin(__builtin_amdgcn_permlane32_swap)
    unsigned xu = __float_as_uint(x);
    auto r = __builtin_amdgcn_permlane32_swap(xu, xu, false, false);
    return (__uint_as_float(r[0]) + __uint_as_float(r[1])) - x;
#else
    return __shfl_xor(x, 32, 64);
#endif
  }
}

template<int LM>
__device__ __forceinline__ float xor_sum(float x) {
  if constexpr (LM == 16) {
#if __has_builtin(__builtin_amdgcn_permlane16_swap)
    unsigned xu = __float_as_uint(x);
    auto r = __builtin_amdgcn_permlane16_swap(xu, xu, false, false);
    return __uint_as_float(r[0]) + __uint_as_float(r[1]);
#else
    return x + __shfl_xor(x, 16, 64);
#endif
  } else if constexpr (LM == 32) {
#if __has_builtin(__builtin_amdgcn_permlane32_swap)
    unsigned xu = __float_as_uint(x);
    auto r = __builtin_amdgcn_permlane32_swap(xu, xu, false, false);
    return __uint_as_float(r[0]) + __uint_as_float(r[1]);
#else
    return x + __shfl_xor(x, 32, 64);
#endif
  } else {
    return x + lane_partner<LM>(x);
  }
}

__device__ __forceinline__ float rdlane(float v, int idx) {
  return __int_as_float(__builtin_amdgcn_readlane(__float_as_int(v), idx));
}

__device__ __forceinline__ float2 cmul(float2 a, float2 b) {
  return make_float2(a.x*b.x - a.y*b.y, a.x*b.y + a.y*b.x);
}
__device__ __forceinline__ float2 cmulc(float2 a, float2 b) {  // a * conj(b)
  return make_float2(a.x*b.x + a.y*b.y, a.y*b.x - a.x*b.y);
}
__device__ __forceinline__ float2 cadd(float2 a, float2 b) {
  return make_float2(a.x + b.x, a.y + b.y);
}

struct S2 { float r, i; };

#define XSLOTS 1088   // 64*17 float2 per buffer

// ---------------- sim14 layers: ONE code copy each (noinline) ----------------
// 6 exchange sites per layer; parity = (site)&1 selects buffer.

__device__ __noinline__ S2 sim14_fwd(S2 v, float ct, float st, int off, int site0) {
  extern __shared__ float2 dxw[];
  const int tid = threadIdx.x;
  const int lane = tid & 63, wv = tid >> 6;
  const int s = wv & 3, q = wv >> 2;
  const int h6 = q & 1, h7 = q >> 1;
  const int sb = lane * 17 + s * 4;
  float vr = v.r, vi = v.i;
  const float sg = 1.f;

  // lane RY gate on wire W (mask 1<<(5-W))
  auto RYL = [&](auto Wc, int idx) {
    constexpr int LM = 1 << (5 - decltype(Wc)::value);
    float c = rdlane(ct, idx), ss = sg * rdlane(st, idx);
    float ls = (lane & LM) ? ss : -ss;
    float pr = lane_partner<LM>(vr), pi = lane_partner<LM>(vi);
    vr = c*vr + ls*pr;  vi = c*vi + ls*pi;
  };
  // fused RY(w6)xRY(w7) quad exchange
  auto QUAD = [&](int i6, int i7, int site) {
    float c6 = rdlane(ct, i6), s6 = sg * rdlane(st, i6);
    float c7 = rdlane(ct, i7), s7 = sg * rdlane(st, i7);
    float r60 = h6 ? s6 : c6, r61 = h6 ? c6 : -s6;
    float r70 = h7 ? s7 : c7, r71 = h7 ? c7 : -s7;
    float2* buf = dxw + (site & 1) * XSLOTS;
    buf[sb + q] = make_float2(vr, vi);
    __syncthreads();
    float2 p0 = buf[sb+0], p1 = buf[sb+1], p2 = buf[sb+2], p3 = buf[sb+3];
    float f0 = r60*r70, f1 = r61*r70, f2 = r60*r71, f3 = r61*r71;
    vr = f0*p0.x + f1*p1.x + f2*p2.x + f3*p3.x;
    vi = f0*p0.y + f1*p1.y + f2*p2.y + f3*p3.y;
  };
  // CRX lane-control C, lane-target T
  auto CRXLL = [&](auto Cc, auto Tc, int idx) {
    constexpr int LC = 1 << (5 - decltype(Cc)::value);
    constexpr int LT = 1 << (5 - decltype(Tc)::value);
    float c = rdlane(ct, idx), ss = sg * rdlane(st, idx);
    bool act = (lane & LC) != 0;
    float cp = act ? c : 1.f, sp = act ? ss : 0.f;
    float pr = lane_partner<LT>(vr), pi = lane_partner<LT>(vi);
    vr = cp*vr + sp*pi;  vi = cp*vi - sp*pr;
  };
  // CRX uniform-control (h), lane-target T
  auto CRXUL = [&](int hact, auto Tc, int idx) {
    if (hact) {
      constexpr int LT = 1 << (5 - decltype(Tc)::value);
      float c = rdlane(ct, idx), ss = sg * rdlane(st, idx);
      float pr = lane_partner<LT>(vr), pi = lane_partner<LT>(vi);
      vr = c*vr + ss*pi;  vi = c*vi - ss*pr;
    }
  };
  // CRX uniform-control (h), wave-target (qmask) — partner same activity
  auto CRXUW = [&](int hact, int qmask, int idx, int site) {
    float2* buf = dxw + (site & 1) * XSLOTS;
    if (hact) buf[sb + q] = make_float2(vr, vi);
    __syncthreads();
    if (hact) {
      float c = rdlane(ct, idx), ss = sg * rdlane(st, idx);
      float2 P = buf[sb + (q ^ qmask)];
      vr = c*vr + ss*P.y;  vi = c*vi - ss*P.x;
    }
  };
  // CRX lane-control C, wave-target (qmask)
  auto CRXLW = [&](auto Cc, int qmask, int idx, int site) {
    constexpr int LC = 1 << (5 - decltype(Cc)::value);
    float c = rdlane(ct, idx), ss = sg * rdlane(st, idx);
    float2* buf = dxw + (site & 1) * XSLOTS;
    buf[sb + q] = make_float2(vr, vi);
    __syncthreads();
    float2 P = buf[sb + (q ^ qmask)];
    bool act = (lane & LC) != 0;
    float cp = act ? c : 1.f, sp = act ? ss : 0.f;
    vr = cp*vr + sp*P.y;  vi = cp*vi - sp*P.x;
  };

  RYL(std::integral_constant<int,0>{}, off+0); RYL(std::integral_constant<int,1>{}, off+1);
  RYL(std::integral_constant<int,2>{}, off+2); RYL(std::integral_constant<int,3>{}, off+3);
  RYL(std::integral_constant<int,4>{}, off+4); RYL(std::integral_constant<int,5>{}, off+5);
  QUAD(off+6, off+7, site0+0);
  CRXUL(h7, std::integral_constant<int,0>{}, off+8);                 // crx(7,0)
  CRXUW(h6, 2, off+9,  site0+1);                                     // crx(6,7)
  CRXLW(std::integral_constant<int,5>{}, 1, off+10, site0+2);        // crx(5,6)
  CRXLL(std::integral_constant<int,4>{}, std::integral_constant<int,5>{}, off+11);
  CRXLL(std::integral_constant<int,3>{}, std::integral_constant<int,4>{}, off+12);
  CRXLL(std::integral_constant<int,2>{}, std::integral_constant<int,3>{}, off+13);
  CRXLL(std::integral_constant<int,1>{}, std::integral_constant<int,2>{}, off+14);
  CRXLL(std::integral_constant<int,0>{}, std::integral_constant<int,1>{}, off+15);
  RYL(std::integral_constant<int,0>{}, off+16); RYL(std::integral_constant<int,1>{}, off+17);
  RYL(std::integral_constant<int,2>{}, off+18); RYL(std::integral_constant<int,3>{}, off+19);
  RYL(std::integral_constant<int,4>{}, off+20); RYL(std::integral_constant<int,5>{}, off+21);
  QUAD(off+22, off+23, site0+3);
  CRXUW(h7, 1, off+24, site0+4);                                     // crx(7,6)
  CRXLW(std::integral_constant<int,0>{}, 2, off+25, site0+5);        // crx(0,7)
  CRXLL(std::integral_constant<int,1>{}, std::integral_constant<int,0>{}, off+26);
  CRXLL(std::integral_constant<int,2>{}, std::integral_constant<int,1>{}, off+27);
  CRXLL(std::integral_constant<int,3>{}, std::integral_constant<int,2>{}, off+28);
  CRXLL(std::integral_constant<int,4>{}, std::integral_constant<int,3>{}, off+29);
  CRXLL(std::integral_constant<int,5>{}, std::integral_constant<int,4>{}, off+30);
  CRXUL(h6, std::integral_constant<int,5>{}, off+31);                // crx(6,5)
  return {vr, vi};
}

__device__ __noinline__ S2 sim14_adj(S2 v, float ct, float st, int off, int site0) {
  extern __shared__ float2 dxw[];
  const int tid = threadIdx.x;
  const int lane = tid & 63, wv = tid >> 6;
  const int s = wv & 3, q = wv >> 2;
  const int h6 = q & 1, h7 = q >> 1;
  const int sb = lane * 17 + s * 4;
  float vr = v.r, vi = v.i;
  const float sg = -1.f;

  auto RYL = [&](auto Wc, int idx) {
    constexpr int LM = 1 << (5 - decltype(Wc)::value);
    float c = rdlane(ct, idx), ss = sg * rdlane(st, idx);
    float ls = (lane & LM) ? ss : -ss;
    float pr = lane_partner<LM>(vr), pi = lane_partner<LM>(vi);
    vr = c*vr + ls*pr;  vi = c*vi + ls*pi;
  };
  auto QUAD = [&](int i6, int i7, int site) {
    float c6 = rdlane(ct, i6), s6 = sg * rdlane(st, i6);
    float c7 = rdlane(ct, i7), s7 = sg * rdlane(st, i7);
    float r60 = h6 ? s6 : c6, r61 = h6 ? c6 : -s6;
    float r70 = h7 ? s7 : c7, r71 = h7 ? c7 : -s7;
    float2* buf = dxw + (site & 1) * XSLOTS;
    buf[sb + q] = make_float2(vr, vi);
    __syncthreads();
    float2 p0 = buf[sb+0], p1 = buf[sb+1], p2 = buf[sb+2], p3 = buf[sb+3];
    float f0 = r60*r70, f1 = r61*r70, f2 = r60*r71, f3 = r61*r71;
    vr = f0*p0.x + f1*p1.x + f2*p2.x + f3*p3.x;
    vi = f0*p0.y + f1*p1.y + f2*p2.y + f3*p3.y;
  };
  auto CRXLL = [&](auto Cc, auto Tc, int idx) {
    constexpr int LC = 1 << (5 - decltype(Cc)::value);
    constexpr int LT = 1 << (5 - decltype(Tc)::value);
    float c = rdlane(ct, idx), ss = sg * rdlane(st, idx);
    bool act = (lane & LC) != 0;
    float cp = act ? c : 1.f, sp = act ? ss : 0.f;
    float pr = lane_partner<LT>(vr), pi = lane_partner<LT>(vi);
    vr = cp*vr + sp*pi;  vi = cp*vi - sp*pr;
  };
  auto CRXUL = [&](int hact, auto Tc, int idx) {
    if (hact) {
      constexpr int LT = 1 << (5 - decltype(Tc)::value);
      float c = rdlane(ct, idx), ss = sg * rdlane(st, idx);
      float pr = lane_partner<LT>(vr), pi = lane_partner<LT>(vi);
      vr = c*vr + ss*pi;  vi = c*vi - ss*pr;
    }
  };
  auto CRXUW = [&](int hact, int qmask, int idx, int site) {
    float2* buf = dxw + (site & 1) * XSLOTS;
    if (hact) buf[sb + q] = make_float2(vr, vi);
    __syncthreads();
    if (hact) {
      float c = rdlane(ct, idx), ss = sg * rdlane(st, idx);
      float2 P = buf[sb + (q ^ qmask)];
      vr = c*vr + ss*P.y;  vi = c*vi - ss*P.x;
    }
  };
  auto CRXLW = [&](auto Cc, int qmask, int idx, int site) {
    constexpr int LC = 1 << (5 - decltype(Cc)::value);
    float c = rdlane(ct, idx), ss = sg * rdlane(st, idx);
    float2* buf = dxw + (site & 1) * XSLOTS;
    buf[sb + q] = make_float2(vr, vi);
    __syncthreads();
    float2 P = buf[sb + (q ^ qmask)];
    bool act = (lane & LC) != 0;
    float cp = act ? c : 1.f, sp = act ? ss : 0.f;
    vr = cp*vr + sp*P.y;  vi = cp*vi - sp*P.x;
  };

  CRXUL(h6, std::integral_constant<int,5>{}, off+31);                // crx(6,5)
  CRXLL(std::integral_constant<int,5>{}, std::integral_constant<int,4>{}, off+30);
  CRXLL(std::integral_constant<int,4>{}, std::integral_constant<int,3>{}, off+29);
  CRXLL(std::integral_constant<int,3>{}, std::integral_constant<int,2>{}, off+28);
  CRXLL(std::integral_constant<int,2>{}, std::integral_constant<int,1>{}, off+27);
  CRXLL(std::integral_constant<int,1>{}, std::integral_constant<int,0>{}, off+26);
  CRXLW(std::integral_constant<int,0>{}, 2, off+25, site0+0);        // crx(0,7)
  CRXUW(h7, 1, off+24, site0+1);                                     // crx(7,6)
  QUAD(off+22, off+23, site0+2);                                     // ry w6,w7 (commute)
  RYL(std::integral_constant<int,5>{}, off+21); RYL(std::integral_constant<int,4>{}, off+20);
  RYL(std::integral_constant<int,3>{}, off+19); RYL(std::integral_constant<int,2>{}, off+18);
  RYL(std::integral_constant<int,1>{}, off+17); RYL(std::integral_constant<int,0>{}, off+16);
  CRXLL(std::integral_constant<int,0>{}, std::integral_constant<int,1>{}, off+15);
  CRXLL(std::integral_constant<int,1>{}, std::integral_constant<int,2>{}, off+14);
  CRXLL(std::integral_constant<int,2>{}, std::integral_constant<int,3>{}, off+13);
  CRXLL(std::integral_constant<int,3>{}, std::integral_constant<int,4>{}, off+12);
  CRXLL(std::integral_constant<int,4>{}, std::integral_constant<int,5>{}, off+11);
  CRXLW(std::integral_constant<int,5>{}, 1, off+10, site0+3);        // crx(5,6)
  CRXUW(h6, 2, off+9, site0+4);                                      // crx(6,7)
  CRXUL(h7, std::integral_constant<int,0>{}, off+8);                 // crx(7,0)
  QUAD(off+6, off+7, site0+5);                                       // ry w6,w7
  RYL(std::integral_constant<int,5>{}, off+5); RYL(std::integral_constant<int,4>{}, off+4);
  RYL(std::integral_constant<int,3>{}, off+3); RYL(std::integral_constant<int,2>{}, off+2);
  RYL(std::integral_constant<int,1>{}, off+1); RYL(std::integral_constant<int,0>{}, off+0);
  return {vr, vi};
}

// ---------------- setup kernel: block-invariant ancilla matrices ----------------

__global__ void setup_kernel(const float* __restrict__ prep_p,
                             const float* __restrict__ sig,
                             const float* __restrict__ qff,
                             float* __restrict__ ws) {
  const int t = threadIdx.x;
  float2 Ga[2][2][2], Gb[2][2][2];
  for (int ly = 0; ly < 2; ++ly)
    for (int qi = 0; qi < 2; ++qi) {
      float y = prep_p[ly*4 + qi*2 + 0], z = prep_p[ly*4 + qi*2 + 1];
      float cy, sy, cz, sz;
      __sincosf(0.5f*y, &sy, &cy);
      __sincosf(0.5f*z, &sz, &cz);
      float2 g00 = make_float2( cy*cz, -cy*sz);
      float2 g01 = make_float2(-sy*cz,  sy*sz);
      float2 g10 = make_float2( sy*cz,  sy*sz);
      float2 g11 = make_float2( cy*cz,  cy*sz);
      if (qi == 0) { Ga[ly][0][0]=g00; Ga[ly][0][1]=g01; Ga[ly][1][0]=g10; Ga[ly][1][1]=g11; }
      else         { Gb[ly][0][0]=g00; Gb[ly][0][1]=g01; Gb[ly][1][0]=g10; Gb[ly][1][1]=g11; }
    }
  float2 M[2][4][4];
  for (int ly = 0; ly < 2; ++ly) {
    float2 T[4][4];
    for (int i = 0; i < 4; ++i)
      for (int j = 0; j < 4; ++j)
        T[i][j] = cmul(Ga[ly][i>>1][j>>1], Gb[ly][i&1][j&1]);
    for (int j = 0; j < 4; ++j) {
      M[ly][0][j] = T[0][j]; M[ly][1][j] = T[1][j];
      M[ly][2][j] = T[3][j]; M[ly][3][j] = T[2][j];
    }
  }
  float2 U[4][4];
  for (int i = 0; i < 4; ++i)
    for (int j = 0; j < 4; ++j) {
      float2 acc = make_float2(0.f, 0.f);
      for (int kk = 0; kk < 4; ++kk) acc = cadd(acc, cmul(M[1][i][kk], M[0][kk][j]));
      U[i][j] = acc;
    }
  float c0n, s0n, c1, s1v, c2, s2v, c3, s3v;
  __sincosf(sig[0], &s0n, &c0n);
  __sincosf(sig[1], &s1v, &c1);
  __sincosf(sig[2], &s2v, &c2);
  __sincosf(sig[3], &s3v, &c3);

  if (t < 16) {
    int i = t >> 2, j = t & 3;   // i = s (row), j = sp (col)
    float2 a1 = make_float2(0.f, 0.f), a2 = make_float2(0.f, 0.f);
    for (int k = 0; k < 4; ++k) {
      float2 tt = cmulc(U[i][k], U[j][k]);
      float sk = (k == 0) ? 1.f : -1.f;
      a1 = cadd(a1, cmul(tt, make_float2(c1, sk*s1v)));
      a2 = cadd(a2, cmul(tt, make_float2(c2, sk*s2v)));
    }
    ((float2*)ws)[t]        = a1;                    // X1[i][j]
    ((float2*)(ws + 32))[t] = a2;                    // X2[i][j]
    float2 d3 = make_float2(c3, (i == 0) ? s3v : -s3v);
    ((float2*)(ws + 64))[t] = cmul(d3, make_float2(U[j][i].x, -U[j][i].y));  // F[i][j]
  }
  if (t < 4) {
    ((float2*)(ws + 96))[t] = cmul(U[t][0], make_float2(c0n, s0n));          // a0[s]
  }
  if (t < 32) {
    float sn, cn;
    __sincosf(0.5f * qff[t], &sn, &cn);
    ((float2*)(ws + 104))[t] = make_float2(cn, sn);                           // qtab
  }
  ws[168 + t] = __expf(-9.210340371976184f * (float)t / 64.f);                // freqs
}

// ---------------- cooperative-row MLP layer (16 waves share rows) ----------------
// MODE: 0 = silu->yl, 1 = raw->yl, 2 = seltab ((float2*)yl)

template<int IN, int NP, int MODE>
__device__ __forceinline__ void mlp_layer(const float* __restrict__ W,
    const float* __restrict__ bias, const float* xl, float* yl,
    int rbase, int lane)
{
  const int sub = lane & 7;
  const int g   = lane >> 3;
#pragma unroll
  for (int p = 0; p < NP; ++p) {
    const int row = rbase + p * 8 + g;
    const float4* w4 = (const float4*)(W + row * IN) + sub;
    const float4* x4 = (const float4*)xl + sub;
    float acc = 0.f;
#pragma unroll
    for (int it = 0; it < IN / 32; ++it) {
      float4 w = w4[it * 8], e = x4[it * 8];
      acc += w.x*e.x + w.y*e.y + w.z*e.z + w.w*e.w;
    }
    acc = xor_sum<1>(acc);
    acc = xor_sum<2>(acc);
    acc = xor_sum<4>(acc);
    if (sub == 0) {
      float a = acc + bias[row];
      if constexpr (MODE == 0) {
        yl[row] = a / (1.f + __expf(-a));
      } else if constexpr (MODE == 1) {
        yl[row] = a;
      } else {
        float th = PI_F / (1.f + __expf(-a));   // theta/2 = pi * sigmoid(a)
        float sn, cn;
        __sincosf(th, &sn, &cn);
        ((float2*)yl)[row] = make_float2(cn, sn);
      }
    }
  }
}

// ---------------- main kernel: 1024 threads = 16 waves, one batch elem/block ----------------

__global__ __launch_bounds__(1024) void qsvt_kernel(
    const float* __restrict__ z_t, const float* __restrict__ t,
    const float* __restrict__ te_w1, const float* __restrict__ te_b1,
    const float* __restrict__ te_w2, const float* __restrict__ te_b2,
    const float* __restrict__ ip_w1, const float* __restrict__ ip_b1,
    const float* __restrict__ ip_w2, const float* __restrict__ ip_b2,
    const float* __restrict__ A_obs, const float* __restrict__ B_obs,
    const float* __restrict__ D_obs,
    const float* __restrict__ head_w, const float* __restrict__ head_b,
    const float* __restrict__ ws,
    float* __restrict__ out)
{
  __shared__ __align__(16) float emb[128];
  __shared__ __align__(16) float y1[128];
  __shared__ __align__(16) float hbuf[256];
  __shared__ __align__(16) float h1[256];
  __shared__ __align__(16) float2 seltab[256];   // [s*64+g] -> (cos(th/2), sin(th/2))
  __shared__ __align__(16) float dumpR[4][256];
  __shared__ __align__(16) float dumpI[4][256];
  __shared__ float redbuf[NOBS][2];
  __shared__ float hdc[NOBS][3], hxc[NOBS][6], hyc[NOBS][6];
  __shared__ __align__(16) float shw[128 * NOBS];
  __shared__ __align__(16) float shb[128];
  extern __shared__ float2 dxw[];                // 2 * XSLOTS exchange slots

  const int tid  = threadIdx.x;
  const int lane = tid & 63;
  const int wv   = tid >> 6;   // 0..15
  const int s    = wv & 3;     // ancilla value
  const int q    = wv >> 2;    // h7*2 + h6
  const int h6   = q & 1;
  const int h7   = q >> 1;
  const int b    = blockIdx.x;

  // ===== Phase A: MLP (cooperative rows, 16 waves) =====
  if (tid < 128) {
    float fr = ws[168 + (tid & 63)];
    float arg = t[b] * fr;
    float sn, cn;
    __sincosf(arg, &sn, &cn);
    emb[tid] = (tid < 64) ? cn : sn;
  }
  __syncthreads();

  mlp_layer<128, 1, 0>(te_w1, te_b1, emb, y1, wv * 8, lane);
  if (tid < 128) hbuf[tid] = z_t[b * 128 + tid];
  __syncthreads();

  mlp_layer<128, 1, 1>(te_w2, te_b2, y1, hbuf + 128, wv * 8, lane);
  __syncthreads();

  mlp_layer<256, 2, 0>(ip_w1, ip_b1, hbuf, h1, wv * 16, lane);
  __syncthreads();

  mlp_layer<256, 2, 2>(ip_w2, ip_b2, h1, (float*)seltab, wv * 16, lane);

  // prefetch observable + head coefficients into LDS (off the tail path)
  if (tid < NOBS * 6)      { hxc[tid/6][tid%6] = A_obs[tid]; hyc[tid/6][tid%6] = B_obs[tid]; }
  else if (tid >= 64 && tid < 64 + NOBS*3) { int qd = tid - 64; hdc[qd/3][qd%3] = 2.f * D_obs[(qd/3)*4 + (qd%3) + 1]; }
#pragma unroll
  for (int i = tid; i < 128*NOBS; i += 1024) shw[i] = head_w[i];
  if (tid < 128) shb[tid] = head_b[tid];
  __syncthreads();  // seltab/coefs visible to all waves

  // per-wave angle tables in registers (lane g <-> gate g)
  float2 mycs = seltab[(s << 6) | lane];
  float selc = mycs.x, sels = mycs.y;
  float2 myq = ((const float2*)(ws + 104))[lane & 31];
  float qc = myq.x, qs = myq.y;

  // ===== Phase C: circuit. init: only m=0 (lane0, q=0) nonzero =====
  S2 v;
  v.r = 0.f; v.i = 0.f;
  if (lane == 0 && q == 0) {
    float2 a0 = ((const float2*)(ws + 96))[s];
    v.r = a0.x; v.i = a0.y;
  }

  const int sb = lane * 17 + s * 4;

  // exchange-site numbering: 6 per sim14 pass, 1 per ancilla mix
  // select_0 (fwd)
  v = sim14_fwd(v, selc, sels, 0, 0);
  v = sim14_fwd(v, selc, sels, 32, 6);
  // ancilla mix X1 (site 12)
  {
    const float2* R = (const float2*)ws + (s << 2);
    float2* buf = dxw + (12 & 1) * XSLOTS;
    buf[sb + q] = make_float2(v.r, v.i);
    __syncthreads();
    float2 o = cmul(R[0], buf[lane*17 + 0*4 + q]);
    o = cadd(o, cmul(R[1], buf[lane*17 + 1*4 + q]));
    o = cadd(o, cmul(R[2], buf[lane*17 + 2*4 + q]));
    o = cadd(o, cmul(R[3], buf[lane*17 + 3*4 + q]));
    v.r = o.x; v.i = o.y;
  }
  // select_1 (adjoint)
  v = sim14_adj(v, selc, sels, 32, 13);
  v = sim14_adj(v, selc, sels, 0, 19);
  // ancilla mix X2 (site 25)
  {
    const float2* R = (const float2*)(ws + 32) + (s << 2);
    float2* buf = dxw + (25 & 1) * XSLOTS;
    buf[sb + q] = make_float2(v.r, v.i);
    __syncthreads();
    float2 o = cmul(R[0], buf[lane*17 + 0*4 + q]);
    o = cadd(o, cmul(R[1], buf[lane*17 + 1*4 + q]));
    o = cadd(o, cmul(R[2], buf[lane*17 + 2*4 + q]));
    o = cadd(o, cmul(R[3], buf[lane*17 + 3*4 + q]));
    v.r = o.x; v.i = o.y;
  }
  // select_2 (fwd)
  v = sim14_fwd(v, selc, sels, 0, 26);
  v = sim14_fwd(v, selc, sels, 32, 32);
  // ancilla mix F (site 38)
  {
    const float2* R = (const float2*)(ws + 64) + (s << 2);
    float2* buf = dxw + (38 & 1) * XSLOTS;
    buf[sb + q] = make_float2(v.r, v.i);
    __syncthreads();
    float2 o = cmul(R[0], buf[lane*17 + 0*4 + q]);
    o = cadd(o, cmul(R[1], buf[lane*17 + 1*4 + q]));
    o = cadd(o, cmul(R[2], buf[lane*17 + 2*4 + q]));
    o = cadd(o, cmul(R[3], buf[lane*17 + 3*4 + q]));
    v.r = o.x; v.i = o.y;
  }
  // final sim14 layer with qff angles (uniform across s)
  v = sim14_fwd(v, qc, qs, 0, 39);

  // ===== Phase D: dump state, observables =====
  {
    int m = (lane << 2) | (h6 << 1) | h7;
    dumpR[s][m] = v.r;
    dumpI[s][m] = v.i;
  }
  __syncthreads();

  // wave wv handles observable w = wv&7 (skip w==7), s-half sh = wv>>3
  {
    const int w = wv & 7, sh = wv >> 3;
    if (w < NOBS) {
      const int pb = 6 - w;
      int g = lane;
      int ib = ((g >> pb) << (pb + 2)) | (g & ((1 << pb) - 1));
      float a = 0.f;
#pragma unroll
      for (int si = 0; si < 2; ++si) {
        const int s2 = sh * 2 + si;
        float xr[4], xi[4];
#pragma unroll
        for (int i = 0; i < 4; ++i) { xr[i] = dumpR[s2][ib + (i << pb)]; xi[i] = dumpI[s2][ib + (i << pb)]; }
        a += hdc[w][0] * (xr[0]*xr[0] + xi[0]*xi[0])
           + hdc[w][1] * (xr[1]*xr[1] + xi[1]*xi[1])
           + hdc[w][2] * (xr[2]*xr[2] + xi[2]*xi[2]);
        const int oi[6] = {1, 2, 2, 3, 3, 3};
        const int oj[6] = {0, 0, 1, 0, 1, 2};
#pragma unroll
        for (int k2 = 0; k2 < 6; ++k2) {
          int i = oi[k2], j = oj[k2];
          float rr = xr[i]*xr[j] + xi[i]*xi[j];   // Re(conj(v_i) v_j)
          float ii = xr[i]*xi[j] - xi[i]*xr[j];   // Im(conj(v_i) v_j)
          a += 2.f * (hxc[w][k2]*rr - hyc[w][k2]*ii);
        }
      }
      a = xor_sum<32>(a);
      a = xor_sum<16>(a);
      a = xor_sum<8>(a);
      a = xor_sum<4>(a);
      a = xor_sum<2>(a);
      a = xor_sum<1>(a);
      if (lane == 0) redbuf[w][sh] = a;
    }
  }
  __syncthreads();

  // ===== Phase E: head =====
  if (tid < 128) {
    float acc = shb[tid];
#pragma unroll
    for (int w = 0; w < NOBS; ++w) {
      float ev = redbuf[w][0] + redbuf[w][1];
      acc += ev * shw[tid*NOBS + w];
    }
    out[b * 128 + tid] = acc;
  }
}

extern "C" void kernel_launch(void* const* d_in, const int* in_sizes, int n_in,
                              void* d_out, int out_size, void* d_ws, size_t ws_size,
                              hipStream_t stream) {
  (void)n_in; (void)out_size; (void)ws_size;
  const float* z_t    = (const float*)d_in[0];
  const float* t      = (const float*)d_in[1];
  const float* te_w1  = (const float*)d_in[2];
  const float* te_b1  = (const float*)d_in[3];
  const float* te_w2  = (const float*)d_in[4];
  const float* te_b2  = (const float*)d_in[5];
  const float* ip_w1  = (const float*)d_in[6];
  const float* ip_b1  = (const float*)d_in[7];
  const float* ip_w2  = (const float*)d_in[8];
  const float* ip_b2  = (const float*)d_in[9];
  const float* prep_p = (const float*)d_in[10];
  const float* sig    = (const float*)d_in[11];
  const float* qff    = (const float*)d_in[12];
  const float* A_obs  = (const float*)d_in[13];
  const float* B_obs  = (const float*)d_in[14];
  const float* D_obs  = (const float*)d_in[15];
  const float* head_w = (const float*)d_in[16];
  const float* head_b = (const float*)d_in[17];
  float* out = (float*)d_out;
  float* ws  = (float*)d_ws;

  setup_kernel<<<1, 64, 0, stream>>>(prep_p, sig, qff, ws);

  int B = in_sizes[1];  // t is (B,)
  size_t dyn = 2 * XSLOTS * sizeof(float2);
  qsvt_kernel<<<B, 1024, dyn, stream>>>(
      z_t, t, te_w1, te_b1, te_w2, te_b2, ip_w1, ip_b1, ip_w2, ip_b2,
      A_obs, B_obs, D_obs, head_w, head_b, ws, out);
}

// Round 11
// 123.980 us; speedup vs baseline: 1.0593x; 1.0593x over previous
//
#include <hip/hip_runtime.h>
#include <math.h>

#define NOBS 7
#define PI_F 3.14159265358979f

// ---- Layout (round-8 winner, reverted from R9/R10 experiments) ----
// Block = 512 threads = 8 waves. Wave wv = h*4 + s : s = ancilla value (0..3),
// h = wire-6 value (0..1). Each wave holds 128 main-register amplitudes:
// main index m (8 bits, wire w -> bit 7-w) = (lane<<2) | (h<<1) | r,
// lane bits = wires 0..5 (lane bit 5-w), h = wire6, r (reg, 2 amps/lane) = wire7.
// Wire-6 exchanges + ancilla mixes share one double-buffered dynamic-LDS
// exchange buffer; buffer parity = site&1, sites strictly sequential, one
// __syncthreads per site (write -> barrier -> read; reuse of same-parity
// buffer is >= 1 barrier after its last read -> race-free).

// ---- VALU-only cross-lane xor exchange ----
template<int LM>
__device__ __forceinline__ float lane_partner(float x) {
  if constexpr (LM == 1) {
    return __int_as_float(__builtin_amdgcn_mov_dpp(__float_as_int(x), 0xB1, 0xF, 0xF, true));
  } else if constexpr (LM == 2) {
    return __int_as_float(__builtin_amdgcn_mov_dpp(__float_as_int(x), 0x4E, 0xF, 0xF, true));
  } else if constexpr (LM == 4) {
    int a = __builtin_amdgcn_mov_dpp(__float_as_int(x), 0x1B, 0xF, 0xF, true);   // xor3
    return __int_as_float(__builtin_amdgcn_mov_dpp(a, 0x141, 0xF, 0xF, true));   // xor7 -> net xor4
  } else if constexpr (LM == 8) {
    int a = __builtin_amdgcn_mov_dpp(__float_as_int(x), 0x141, 0xF, 0xF, true);  // xor7
    return __int_as_float(__builtin_amdgcn_mov_dpp(a, 0x140, 0xF, 0xF, true));   // xor15 -> net xor8
  } else if constexpr (LM == 16) {
#if __has_builtin(__builtin_amdgcn_permlane16_swap)
    unsigned xu = __float_as_uint(x);
    auto r = __builtin_amdgcn_permlane16_swap(xu, xu, false, false);
    return (__uint_as_float(r[0]) + __uint_as_float(r[1])) - x;
#else
    return __shfl_xor(x, 16, 64);
#endif
  } else {
#if __has_builtin(__builtin_amdgcn_permlane32_swap)
    unsigned xu = __float_as_uint(x);
    auto r = __builtin_amdgcn_permlane32_swap(xu, xu, false, false);
    return (__uint_as_float(r[0]) + __uint_as_float(r[1])) - x;
#else
    return __shfl_xor(x, 32, 64);
#endif
  }
}

template<int LM>
__device__ __forceinline__ float xor_sum(float x) {
  if constexpr (LM == 16) {
#if __has_builtin(__builtin_amdgcn_permlane16_swap)
    unsigned xu = __float_as_uint(x);
    auto r = __builtin_amdgcn_permlane16_swap(xu, xu, false, false);
    return __uint_as_float(r[0]) + __uint_as_float(r[1]);
#else
    return x + __shfl_xor(x, 16, 64);
#endif
  } else if constexpr (LM == 32) {
#if __has_builtin(__builtin_amdgcn_permlane32_swap)
    unsigned xu = __float_as_uint(x);
    auto r = __builtin_amdgcn_permlane32_swap(xu, xu, false, false);
    return __uint_as_float(r[0]) + __uint_as_float(r[1]);
#else
    return x + __shfl_xor(x, 32, 64);
#endif
  } else {
    return x + lane_partner<LM>(x);
  }
}

__device__ __forceinline__ float rdlane(float v, int idx) {
  return __int_as_float(__builtin_amdgcn_readlane(__float_as_int(v), idx));
}

__device__ __forceinline__ float2 cmul(float2 a, float2 b) {
  return make_float2(a.x*b.x - a.y*b.y, a.x*b.y + a.y*b.x);
}
__device__ __forceinline__ float2 cmulc(float2 a, float2 b) {  // a * conj(b)
  return make_float2(a.x*b.x + a.y*b.y, a.y*b.x - a.x*b.y);
}
__device__ __forceinline__ float2 cadd(float2 a, float2 b) {
  return make_float2(a.x + b.x, a.y + b.y);
}

struct S4 { float r0, r1, i0, i1; };

// exchange with sibling wave (wv^4); one barrier; parity = site&1
__device__ __forceinline__ float4 wexch(int site, int wv, int lane,
                                        const float* vr, const float* vi) {
  extern __shared__ float4 dxw[];   // 2 * 512 entries (16 KB dynamic)
  float4* buf = dxw + (site & 1) * 512;
  buf[wv * 64 + lane] = make_float4(vr[0], vr[1], vi[0], vi[1]);
  __syncthreads();
  return buf[(wv ^ 4) * 64 + lane];
}

// ---------------- gate helpers (2 amps/lane) ----------------

template<int W>
__device__ __forceinline__ void ry_lane_g(float* vr, float* vi, int lane,
                                          float ct, float st, int idx, float sg) {
  float c = rdlane(ct, idx), s = sg * rdlane(st, idx);
  constexpr int LM = 1 << (5 - W);
  const float ls = (lane & LM) ? s : -s;
#pragma unroll
  for (int r = 0; r < 2; ++r) {
    float pr = lane_partner<LM>(vr[r]);
    float pi = lane_partner<LM>(vi[r]);
    vr[r] = c*vr[r] + ls*pr;
    vi[r] = c*vi[r] + ls*pi;
  }
}

__device__ __forceinline__ void ry_wave6_g(float* vr, float* vi, int wv, int lane, int h,
                                           float ct, float st, int idx, float sg, int site) {
  float c = rdlane(ct, idx), s = sg * rdlane(st, idx);
  float4 P = wexch(site, wv, lane, vr, vi);
  const float ls = h ? s : -s;
  vr[0] = c*vr[0] + ls*P.x;  vr[1] = c*vr[1] + ls*P.y;
  vi[0] = c*vi[0] + ls*P.z;  vi[1] = c*vi[1] + ls*P.w;
}

__device__ __forceinline__ void ry_reg7_g(float* vr, float* vi,
                                          float ct, float st, int idx, float sg) {
  float c = rdlane(ct, idx), s = sg * rdlane(st, idx);
  float a0 = vr[0], a1 = vr[1];
  vr[0] = c*a0 - s*a1;  vr[1] = s*a0 + c*a1;
  float b0 = vi[0], b1 = vi[1];
  vi[0] = c*b0 - s*b1;  vi[1] = s*b0 + c*b1;
}

template<int C, int T>
__device__ __forceinline__ void crx_ll_g(float* vr, float* vi, int lane,
                                         float ct, float st, int idx, float sg) {
  float c = rdlane(ct, idx), s = sg * rdlane(st, idx);
  constexpr int LC = 1 << (5 - C), LT = 1 << (5 - T);
  const bool act = (lane & LC) != 0;
  const float cp = act ? c : 1.f, sp = act ? s : 0.f;
#pragma unroll
  for (int r = 0; r < 2; ++r) {
    float pr = lane_partner<LT>(vr[r]);
    float pi = lane_partner<LT>(vi[r]);
    vr[r] = cp*vr[r] + sp*pi;
    vi[r] = cp*vi[r] - sp*pr;
  }
}

template<int T>
__device__ __forceinline__ void crx_7l_g(float* vr, float* vi,
                                         float ct, float st, int idx, float sg) {
  float c = rdlane(ct, idx), s = sg * rdlane(st, idx);
  constexpr int LT = 1 << (5 - T);
  float pr = lane_partner<LT>(vr[1]);
  float pi = lane_partner<LT>(vi[1]);
  vr[1] = c*vr[1] + s*pi;
  vi[1] = c*vi[1] - s*pr;
}

template<int C>
__device__ __forceinline__ void crx_l7_g(float* vr, float* vi, int lane,
                                         float ct, float st, int idx, float sg) {
  float c = rdlane(ct, idx), s = sg * rdlane(st, idx);
  constexpr int LC = 1 << (5 - C);
  const bool act = (lane & LC) != 0;
  const float cp = act ? c : 1.f, sp = act ? s : 0.f;
  float xr = vr[0], xi = vi[0], yr = vr[1], yi = vi[1];
  vr[0] = cp*xr + sp*yi;  vi[0] = cp*xi - sp*yr;
  vr[1] = cp*yr + sp*xi;  vi[1] = cp*yi - sp*xr;
}

template<int C>
__device__ __forceinline__ void crx_l6_g(float* vr, float* vi, int wv, int lane,
                                         float ct, float st, int idx, float sg, int site) {
  float c = rdlane(ct, idx), s = sg * rdlane(st, idx);
  float4 P = wexch(site, wv, lane, vr, vi);
  constexpr int LC = 1 << (5 - C);
  const bool act = (lane & LC) != 0;
  const float cp = act ? c : 1.f, sp = act ? s : 0.f;
  vr[0] = cp*vr[0] + sp*P.z;  vi[0] = cp*vi[0] - sp*P.x;
  vr[1] = cp*vr[1] + sp*P.w;  vi[1] = cp*vi[1] - sp*P.y;
}

__device__ __forceinline__ void crx_67_g(float* vr, float* vi, int h,
                                         float ct, float st, int idx, float sg) {
  if (h) {
    float c = rdlane(ct, idx), s = sg * rdlane(st, idx);
    float xr = vr[0], xi = vi[0], yr = vr[1], yi = vi[1];
    vr[0] = c*xr + s*yi;  vi[0] = c*xi - s*yr;
    vr[1] = c*yr + s*xi;  vi[1] = c*yi - s*xr;
  }
}

template<int T>
__device__ __forceinline__ void crx_6l_g(float* vr, float* vi, int h,
                                         float ct, float st, int idx, float sg) {
  if (h) {
    float c = rdlane(ct, idx), s = sg * rdlane(st, idx);
    constexpr int LT = 1 << (5 - T);
#pragma unroll
    for (int r = 0; r < 2; ++r) {
      float pr = lane_partner<LT>(vr[r]);
      float pi = lane_partner<LT>(vi[r]);
      vr[r] = c*vr[r] + s*pi;
      vi[r] = c*vi[r] - s*pr;
    }
  }
}

// Fused RY(w6,ia) -> RY(w7,ib) -> CRX(7,6;ic): ONE exchange instead of two.
// All three act on wires {6,7}; with own+partner regs we have the full 4-dim
// subspace locally.
__device__ __forceinline__ void trio_fwd(float* vr, float* vi, int wv, int lane, int h,
                                         float ct, float st, int ia, int ib, int ic,
                                         float sg, int site) {
  float ca = rdlane(ct, ia), sa = sg * rdlane(st, ia);
  float cb = rdlane(ct, ib), sb = sg * rdlane(st, ib);
  float cc = rdlane(ct, ic), sc = sg * rdlane(st, ic);
  float4 P = wexch(site, wv, lane, vr, vi);   // partner (h^1): x=pr0 y=pr1 z=pi0 w=pi1
  const float lsa = h ? sa : -sa;
  // RY6: b_own_r = ca*a_r + lsa*p_r ; b_par_r = ca*p_r - lsa*a_r
  float bor0 = ca*vr[0] + lsa*P.x, boi0 = ca*vi[0] + lsa*P.z;
  float bor1 = ca*vr[1] + lsa*P.y, boi1 = ca*vi[1] + lsa*P.w;
  float bpr0 = ca*P.x - lsa*vr[0], bpi0 = ca*P.z - lsa*vi[0];
  float bpr1 = ca*P.y - lsa*vr[1], bpi1 = ca*P.w - lsa*vi[1];
  // RY7 on regs
  float cor0 = cb*bor0 - sb*bor1, coi0 = cb*boi0 - sb*boi1;
  float cor1 = sb*bor0 + cb*bor1, coi1 = sb*boi0 + cb*boi1;
  float cpr1 = sb*bpr0 + cb*bpr1, cpi1 = sb*bpi0 + cb*bpi1;
  // CRX(ctrl w7=r1, tgt w6): r=1 mixes with partner's r=1
  vr[0] = cor0;                 vi[0] = coi0;
  vr[1] = cc*cor1 + sc*cpi1;    vi[1] = cc*coi1 - sc*cpr1;
}

// Adjoint mirror: CRX(7,6;ic) -> RY(w7,ib) -> RY(w6,ia), with sg=-1 folded in.
__device__ __forceinline__ void trio_adj(float* vr, float* vi, int wv, int lane, int h,
                                         float ct, float st, int ia, int ib, int ic,
                                         float sg, int site) {
  float ca = rdlane(ct, ia), sa = sg * rdlane(st, ia);
  float cb = rdlane(ct, ib), sb = sg * rdlane(st, ib);
  float cc = rdlane(ct, ic), sc = sg * rdlane(st, ic);
  float4 P = wexch(site, wv, lane, vr, vi);
  // CRX on r=1 for own and partner
  float dor1 = cc*vr[1] + sc*P.w,   doi1 = cc*vi[1] - sc*P.y;
  float dpr1 = cc*P.y + sc*vi[1],   dpi1 = cc*P.w - sc*vr[1];
  // RY7 on regs (d_0 = original r0 values)
  float eor0 = cb*vr[0] - sb*dor1,  eoi0 = cb*vi[0] - sb*doi1;
  float eor1 = sb*vr[0] + cb*dor1,  eoi1 = sb*vi[0] + cb*doi1;
  float epr0 = cb*P.x  - sb*dpr1,   epi0 = cb*P.z  - sb*dpi1;
  float epr1 = sb*P.x  + cb*dpr1,   epi1 = sb*P.z  + cb*dpi1;
  // RY6 across wave pair
  const float lsa = h ? sa : -sa;
  vr[0] = ca*eor0 + lsa*epr0;  vi[0] = ca*eoi0 + lsa*epi0;
  vr[1] = ca*eor1 + lsa*epr1;  vi[1] = ca*eoi1 + lsa*epi1;
}

// ---------------- sim14 layers: ONE code copy each (noinline) ----------------
// 3 exchange sites per pass.

__device__ __noinline__ S4 sim14_fwd(S4 v, float ct, float st, int off, int site0) {
  const int tid = threadIdx.x;
  const int lane = tid & 63, wv = tid >> 6, h = wv >> 2;
  float vr[2] = {v.r0, v.r1}, vi[2] = {v.i0, v.i1};
  const float sg = 1.f;
  ry_lane_g<0>(vr,vi,lane,ct,st,off+0,sg); ry_lane_g<1>(vr,vi,lane,ct,st,off+1,sg);
  ry_lane_g<2>(vr,vi,lane,ct,st,off+2,sg); ry_lane_g<3>(vr,vi,lane,ct,st,off+3,sg);
  ry_lane_g<4>(vr,vi,lane,ct,st,off+4,sg); ry_lane_g<5>(vr,vi,lane,ct,st,off+5,sg);
  ry_wave6_g(vr,vi,wv,lane,h,ct,st,off+6,sg,site0+0);
  ry_reg7_g(vr,vi,ct,st,off+7,sg);
  crx_7l_g<0>(vr,vi,ct,st,off+8,sg);
  crx_67_g(vr,vi,h,ct,st,off+9,sg);
  crx_l6_g<5>(vr,vi,wv,lane,ct,st,off+10,sg,site0+1);
  crx_ll_g<4,5>(vr,vi,lane,ct,st,off+11,sg); crx_ll_g<3,4>(vr,vi,lane,ct,st,off+12,sg);
  crx_ll_g<2,3>(vr,vi,lane,ct,st,off+13,sg); crx_ll_g<1,2>(vr,vi,lane,ct,st,off+14,sg);
  crx_ll_g<0,1>(vr,vi,lane,ct,st,off+15,sg);
  ry_lane_g<0>(vr,vi,lane,ct,st,off+16,sg); ry_lane_g<1>(vr,vi,lane,ct,st,off+17,sg);
  ry_lane_g<2>(vr,vi,lane,ct,st,off+18,sg); ry_lane_g<3>(vr,vi,lane,ct,st,off+19,sg);
  ry_lane_g<4>(vr,vi,lane,ct,st,off+20,sg); ry_lane_g<5>(vr,vi,lane,ct,st,off+21,sg);
  trio_fwd(vr,vi,wv,lane,h,ct,st,off+22,off+23,off+24,sg,site0+2);
  crx_l7_g<0>(vr,vi,lane,ct,st,off+25,sg);
  crx_ll_g<1,0>(vr,vi,lane,ct,st,off+26,sg); crx_ll_g<2,1>(vr,vi,lane,ct,st,off+27,sg);
  crx_ll_g<3,2>(vr,vi,lane,ct,st,off+28,sg); crx_ll_g<4,3>(vr,vi,lane,ct,st,off+29,sg);
  crx_ll_g<5,4>(vr,vi,lane,ct,st,off+30,sg);
  crx_6l_g<5>(vr,vi,h,ct,st,off+31,sg);
  return {vr[0], vr[1], vi[0], vi[1]};
}

__device__ __noinline__ S4 sim14_adj(S4 v, float ct, float st, int off, int site0) {
  const int tid = threadIdx.x;
  const int lane = tid & 63, wv = tid >> 6, h = wv >> 2;
  float vr[2] = {v.r0, v.r1}, vi[2] = {v.i0, v.i1};
  const float sg = -1.f;
  crx_6l_g<5>(vr,vi,h,ct,st,off+31,sg);
  crx_ll_g<5,4>(vr,vi,lane,ct,st,off+30,sg); crx_ll_g<4,3>(vr,vi,lane,ct,st,off+29,sg);
  crx_ll_g<3,2>(vr,vi,lane,ct,st,off+28,sg); crx_ll_g<2,1>(vr,vi,lane,ct,st,off+27,sg);
  crx_ll_g<1,0>(vr,vi,lane,ct,st,off+26,sg);
  crx_l7_g<0>(vr,vi,lane,ct,st,off+25,sg);
  trio_adj(vr,vi,wv,lane,h,ct,st,off+22,off+23,off+24,sg,site0+0);
  ry_lane_g<5>(vr,vi,lane,ct,st,off+21,sg); ry_lane_g<4>(vr,vi,lane,ct,st,off+20,sg);
  ry_lane_g<3>(vr,vi,lane,ct,st,off+19,sg); ry_lane_g<2>(vr,vi,lane,ct,st,off+18,sg);
  ry_lane_g<1>(vr,vi,lane,ct,st,off+17,sg); ry_lane_g<0>(vr,vi,lane,ct,st,off+16,sg);
  crx_ll_g<0,1>(vr,vi,lane,ct,st,off+15,sg); crx_ll_g<1,2>(vr,vi,lane,ct,st,off+14,sg);
  crx_ll_g<2,3>(vr,vi,lane,ct,st,off+13,sg); crx_ll_g<3,4>(vr,vi,lane,ct,st,off+12,sg);
  crx_ll_g<4,5>(vr,vi,lane,ct,st,off+11,sg);
  crx_l6_g<5>(vr,vi,wv,lane,ct,st,off+10,sg,site0+1);
  crx_67_g(vr,vi,h,ct,st,off+9,sg);
  crx_7l_g<0>(vr,vi,ct,st,off+8,sg);
  ry_reg7_g(vr,vi,ct,st,off+7,sg);
  ry_wave6_g(vr,vi,wv,lane,h,ct,st,off+6,sg,site0+2);
  ry_lane_g<5>(vr,vi,lane,ct,st,off+5,sg); ry_lane_g<4>(vr,vi,lane,ct,st,off+4,sg);
  ry_lane_g<3>(vr,vi,lane,ct,st,off+3,sg); ry_lane_g<2>(vr,vi,lane,ct,st,off+2,sg);
  ry_lane_g<1>(vr,vi,lane,ct,st,off+1,sg); ry_lane_g<0>(vr,vi,lane,ct,st,off+0,sg);
  return {vr[0], vr[1], vi[0], vi[1]};
}

// ---------------- cooperative-row MLP layer (8 waves share rows) ----------------
// MODE: 0 = silu->yl, 1 = raw->yl, 2 = seltab ((float2*)yl)

template<int IN, int NP, int MODE>
__device__ __forceinline__ void mlp_layer(const float* __restrict__ W,
    const float* __restrict__ bias, const float* xl, float* yl,
    int rbase, int lane)
{
  const int sub = lane & 7;
  const int g   = lane >> 3;
#pragma unroll
  for (int p = 0; p < NP; ++p) {
    const int row = rbase + p * 8 + g;
    const float4* w4 = (const float4*)(W + row * IN) + sub;
    const float4* x4 = (const float4*)xl + sub;
    float acc = 0.f;
#pragma unroll
    for (int it = 0; it < IN / 32; ++it) {
      float4 w = w4[it * 8], e = x4[it * 8];
      acc += w.x*e.x + w.y*e.y + w.z*e.z + w.w*e.w;
    }
    acc = xor_sum<1>(acc);
    acc = xor_sum<2>(acc);
    acc = xor_sum<4>(acc);
    if (sub == 0) {
      float a = acc + bias[row];
      if constexpr (MODE == 0) {
        yl[row] = a / (1.f + __expf(-a));
      } else if constexpr (MODE == 1) {
        yl[row] = a;
      } else {
        float th = PI_F / (1.f + __expf(-a));   // theta/2 = pi * sigmoid(a)
        float sn, cn;
        __sincosf(th, &sn, &cn);
        ((float2*)yl)[row] = make_float2(cn, sn);
      }
    }
  }
}

// ---------------- main kernel: 512 threads = 8 waves, one batch elem/block ----------------

__global__ __launch_bounds__(512) void qsvt_kernel(
    const float* __restrict__ z_t, const float* __restrict__ t,
    const float* __restrict__ te_w1, const float* __restrict__ te_b1,
    const float* __restrict__ te_w2, const float* __restrict__ te_b2,
    const float* __restrict__ ip_w1, const float* __restrict__ ip_b1,
    const float* __restrict__ ip_w2, const float* __restrict__ ip_b2,
    const float* __restrict__ prep_p, const float* __restrict__ sig,
    const float* __restrict__ qff,
    const float* __restrict__ A_obs, const float* __restrict__ B_obs,
    const float* __restrict__ D_obs,
    const float* __restrict__ head_w, const float* __restrict__ head_b,
    float* __restrict__ out)
{
  __shared__ __align__(16) float emb[128];
  __shared__ __align__(16) float y1[128];
  __shared__ __align__(16) float hbuf[256];
  __shared__ __align__(16) float h1[256];
  __shared__ __align__(16) float2 seltab[256];   // [s*64+g] -> (cos(th/2), sin(th/2))
  __shared__ __align__(16) float2 qtab2[32];
  __shared__ __align__(16) float2 sX1[16], sX2[16], sF[16], sa0[4];
  __shared__ __align__(16) float dumpR[4][256];
  __shared__ __align__(16) float dumpI[4][256];
  __shared__ float redbuf[NOBS][4];
  __shared__ float hdc[NOBS][3], hxc[NOBS][6], hyc[NOBS][6];
  __shared__ __align__(16) float shw[128 * NOBS];
  __shared__ __align__(16) float shb[128];
  extern __shared__ float4 dxw[];                // 2 x 512 exchange buffers

  const int tid  = threadIdx.x;
  const int lane = tid & 63;
  const int wv   = tid >> 6;   // 0..7
  const int s    = wv & 3;     // ancilla value
  const int h    = wv >> 2;    // wire-6 value
  const int b    = blockIdx.x;

  // ===== Phase 0: wave 0 builds block-invariant ancilla matrices into LDS =====
  if (tid < 32) {
    float sn, cn;
    __sincosf(0.5f * qff[tid], &sn, &cn);
    qtab2[tid] = make_float2(cn, sn);
  }
  if (wv == 0) {
    float2 Ga[2][2][2], Gb[2][2][2];
    for (int ly = 0; ly < 2; ++ly)
      for (int qi = 0; qi < 2; ++qi) {
        float y = prep_p[ly*4 + qi*2 + 0], z = prep_p[ly*4 + qi*2 + 1];
        float cy, sy, cz, sz;
        __sincosf(0.5f*y, &sy, &cy);
        __sincosf(0.5f*z, &sz, &cz);
        float2 g00 = make_float2( cy*cz, -cy*sz);
        float2 g01 = make_float2(-sy*cz,  sy*sz);
        float2 g10 = make_float2( sy*cz,  sy*sz);
        float2 g11 = make_float2( cy*cz,  cy*sz);
        if (qi == 0) { Ga[ly][0][0]=g00; Ga[ly][0][1]=g01; Ga[ly][1][0]=g10; Ga[ly][1][1]=g11; }
        else         { Gb[ly][0][0]=g00; Gb[ly][0][1]=g01; Gb[ly][1][0]=g10; Gb[ly][1][1]=g11; }
      }
    float2 M[2][4][4];
    for (int ly = 0; ly < 2; ++ly) {
      float2 T[4][4];
      for (int i = 0; i < 4; ++i)
        for (int j = 0; j < 4; ++j)
          T[i][j] = cmul(Ga[ly][i>>1][j>>1], Gb[ly][i&1][j&1]);
      for (int j = 0; j < 4; ++j) {
        M[ly][0][j] = T[0][j]; M[ly][1][j] = T[1][j];
        M[ly][2][j] = T[3][j]; M[ly][3][j] = T[2][j];
      }
    }
    float2 U[4][4];
    for (int i = 0; i < 4; ++i)
      for (int j = 0; j < 4; ++j) {
        float2 acc = make_float2(0.f, 0.f);
        for (int kk = 0; kk < 4; ++kk) acc = cadd(acc, cmul(M[1][i][kk], M[0][kk][j]));
        U[i][j] = acc;
      }
    float c0n, s0n, c1, s1v, c2, s2v, c3, s3v;
    __sincosf(sig[0], &s0n, &c0n);
    __sincosf(sig[1], &s1v, &c1);
    __sincosf(sig[2], &s2v, &c2);
    __sincosf(sig[3], &s3v, &c3);
    if (lane < 16) {
      int i = lane >> 2, j = lane & 3;   // i = s (row), j = sp (col)
      float2 a1 = make_float2(0.f, 0.f), a2 = make_float2(0.f, 0.f);
      for (int k = 0; k < 4; ++k) {
        float2 tt = cmulc(U[i][k], U[j][k]);
        float sk = (k == 0) ? 1.f : -1.f;
        a1 = cadd(a1, cmul(tt, make_float2(c1, sk*s1v)));
        a2 = cadd(a2, cmul(tt, make_float2(c2, sk*s2v)));
      }
      sX1[lane] = a1;
      sX2[lane] = a2;
      float2 d3 = make_float2(c3, (i == 0) ? s3v : -s3v);
      sF[lane] = cmul(d3, make_float2(U[j][i].x, -U[j][i].y));
    }
    if (lane < 4) sa0[lane] = cmul(U[lane][0], make_float2(c0n, s0n));
  }

  // ===== Phase A: MLP (cooperative rows, 8 waves) =====
  if (tid < 128) {
    float fr = __expf(-9.210340371976184f * (float)(tid & 63) / 64.f);
    float arg = t[b] * fr;
    float sn, cn;
    __sincosf(arg, &sn, &cn);
    emb[tid] = (tid < 64) ? cn : sn;
  }
  __syncthreads();

  mlp_layer<128, 2, 0>(te_w1, te_b1, emb, y1, wv * 16, lane);
  if (tid < 128) hbuf[tid] = z_t[b * 128 + tid];
  __syncthreads();

  mlp_layer<128, 2, 1>(te_w2, te_b2, y1, hbuf + 128, wv * 16, lane);
  __syncthreads();

  mlp_layer<256, 4, 0>(ip_w1, ip_b1, hbuf, h1, wv * 32, lane);
  __syncthreads();

  mlp_layer<256, 4, 2>(ip_w2, ip_b2, h1, (float*)seltab, wv * 32, lane);

  // prefetch observable + head coefficients into LDS (off the tail path)
  if (tid < NOBS * 6)      { hxc[tid/6][tid%6] = A_obs[tid]; hyc[tid/6][tid%6] = B_obs[tid]; }
  else if (tid >= 64 && tid < 64 + NOBS*3) { int q = tid - 64; hdc[q/3][q%3] = 2.f * D_obs[(q/3)*4 + (q%3) + 1]; }
#pragma unroll
  for (int i = tid; i < 128*NOBS; i += 512) shw[i] = head_w[i];
  if (tid < 128) shb[tid] = head_b[tid];
  __syncthreads();  // seltab/coefs/matrices visible to all waves

  // per-wave angle tables in registers (lane g <-> gate g)
  float2 mycs = seltab[(s << 6) | lane];
  float selc = mycs.x, sels = mycs.y;
  float2 myq = qtab2[lane & 31];
  float qc = myq.x, qs = myq.y;

  // ===== Phase C: circuit. init = U*D0*|0..0> : only m=0 (lane0,h0,r0) nonzero =====
  S4 v;
  v.r0 = 0.f; v.r1 = 0.f; v.i0 = 0.f; v.i1 = 0.f;
  if (lane == 0 && h == 0) {
    float2 a0 = sa0[s];
    v.r0 = a0.x; v.i0 = a0.y;
  }

  // ancilla mix through the parity-alternating exchange buffer (1 barrier)
  auto ancmix = [&](const float2* R, int site) {
    float4* buf = dxw + (site & 1) * 512;
    buf[wv * 64 + lane] = make_float4(v.r0, v.r1, v.i0, v.i1);
    __syncthreads();
    float2 o0 = make_float2(0.f, 0.f), o1 = make_float2(0.f, 0.f);
#pragma unroll
    for (int sp = 0; sp < 4; ++sp) {
      float4 P = buf[(h * 4 + sp) * 64 + lane];
      float2 Rr = R[sp];
      o0 = cadd(o0, cmul(Rr, make_float2(P.x, P.z)));
      o1 = cadd(o1, cmul(Rr, make_float2(P.y, P.w)));
    }
    v.r0 = o0.x; v.i0 = o0.y; v.r1 = o1.x; v.i1 = o1.y;
  };

  // sites: 3 per sim14 pass, 1 per ancilla mix, strictly sequential
  v = sim14_fwd(v, selc, sels, 0, 0);
  v = sim14_fwd(v, selc, sels, 32, 3);
  ancmix(&sX1[s << 2], 6);
  v = sim14_adj(v, selc, sels, 32, 7);
  v = sim14_adj(v, selc, sels, 0, 10);
  ancmix(&sX2[s << 2], 13);
  v = sim14_fwd(v, selc, sels, 0, 14);
  v = sim14_fwd(v, selc, sels, 32, 17);
  ancmix(&sF[s << 2], 20);
  v = sim14_fwd(v, qc, qs, 0, 21);

  // ===== Phase D: dump state, observables =====
  *(float2*)&dumpR[s][(lane << 2) | (h << 1)] = make_float2(v.r0, v.r1);
  *(float2*)&dumpI[s][(lane << 2) | (h << 1)] = make_float2(v.i0, v.i1);
  __syncthreads();  // obs reads cross h

  // h=0 waves: w 0..3 ; h=1 waves: w 4..6
  const int w0 = h ? 4 : 0, w1 = h ? NOBS : 4;
  for (int w = w0; w < w1; ++w) {
    const int pb = 6 - w;  // wires (w, w+1) -> bits (7-w, 6-w) of m
    int g = lane;
    int ib = ((g >> pb) << (pb + 2)) | (g & ((1 << pb) - 1));
    float xr[4], xi[4];
#pragma unroll
    for (int i = 0; i < 4; ++i) { xr[i] = dumpR[s][ib + (i << pb)]; xi[i] = dumpI[s][ib + (i << pb)]; }
    float a = hdc[w][0] * (xr[0]*xr[0] + xi[0]*xi[0])
            + hdc[w][1] * (xr[1]*xr[1] + xi[1]*xi[1])
            + hdc[w][2] * (xr[2]*xr[2] + xi[2]*xi[2]);
    const int oi[6] = {1, 2, 2, 3, 3, 3};
    const int oj[6] = {0, 0, 1, 0, 1, 2};
#pragma unroll
    for (int k2 = 0; k2 < 6; ++k2) {
      int i = oi[k2], j = oj[k2];
      float rr = xr[i]*xr[j] + xi[i]*xi[j];   // Re(conj(v_i) v_j)
      float ii = xr[i]*xi[j] - xi[i]*xr[j];   // Im(conj(v_i) v_j)
      a += 2.f * (hxc[w][k2]*rr - hyc[w][k2]*ii);
    }
    a = xor_sum<32>(a);
    a = xor_sum<16>(a);
    a = xor_sum<8>(a);
    a = xor_sum<4>(a);
    a = xor_sum<2>(a);
    a = xor_sum<1>(a);
    if (lane == 0) redbuf[w][s] = a;
  }
  __syncthreads();

  // ===== Phase E: head =====
  if (tid < 128) {
    float acc = shb[tid];
#pragma unroll
    for (int w = 0; w < NOBS; ++w) {
      float ev = redbuf[w][0] + redbuf[w][1] + redbuf[w][2] + redbuf[w][3];
      acc += ev * shw[tid*NOBS + w];
    }
    out[b * 128 + tid] = acc;
  }
}

extern "C" void kernel_launch(void* const* d_in, const int* in_sizes, int n_in,
                              void* d_out, int out_size, void* d_ws, size_t ws_size,
                              hipStream_t stream) {
  (void)n_in; (void)out_size; (void)d_ws; (void)ws_size;
  const float* z_t    = (const float*)d_in[0];
  const float* t      = (const float*)d_in[1];
  const float* te_w1  = (const float*)d_in[2];
  const float* te_b1  = (const float*)d_in[3];
  const float* te_w2  = (const float*)d_in[4];
  const float* te_b2  = (const float*)d_in[5];
  const float* ip_w1  = (const float*)d_in[6];
  const float* ip_b1  = (const float*)d_in[7];
  const float* ip_w2  = (const float*)d_in[8];
  const float* ip_b2  = (const float*)d_in[9];
  const float* prep_p = (const float*)d_in[10];
  const float* sig    = (const float*)d_in[11];
  const float* qff    = (const float*)d_in[12];
  const float* A_obs  = (const float*)d_in[13];
  const float* B_obs  = (const float*)d_in[14];
  const float* D_obs  = (const float*)d_in[15];
  const float* head_w = (const float*)d_in[16];
  const float* head_b = (const float*)d_in[17];
  float* out = (float*)d_out;

  int B = in_sizes[1];  // t is (B,)
  size_t dyn = 2 * 512 * sizeof(float4);
  qsvt_kernel<<<B, 512, dyn, stream>>>(
      z_t, t, te_w1, te_b1, te_w2, te_b2, ip_w1, ip_b1, ip_w2, ip_b2,
      prep_p, sig, qff, A_obs, B_obs, D_obs, head_w, head_b, out);
}